// Round 1
// baseline (2024.448 us; speedup 1.0000x reference)
//
#include <hip/hip_runtime.h>

#define D_MODEL 1024
#define NHEAD   16
#define DK      64
#define SEQ     2048
#define BATCH   4
#define NEG_INF (-1e30f)

// ---------------------------------------------------------------------------
// GEMM:  C[m][n] = sum_k A[k][m'] * B[k][n] + bias[n]
// A is K-major: element (k, m) at  A + (m/mpb)*bstrideA + k*lda + (m % mpb)
//   - projections: A = x  (lda=SEQ, bstrideA=D_MODEL*SEQ, mpb=SEQ)
//   - final:       A = attnT (lda=BATCH*SEQ, bstrideA=0, mpb=BATCH*SEQ)
// TOUT=false: C row-major [m][D_MODEL]
// TOUT=true : C is d_out [BATCH][D_MODEL][SEQ], m -> (b = m/SEQ, l = m%SEQ)
// Tile: 128x128, BK=8, 256 threads, 8x8 per thread as 4 blocks of 4x4.
// ---------------------------------------------------------------------------
template<bool TOUT>
__global__ __launch_bounds__(256)
void gemm_atb(const float* __restrict__ A, const float* __restrict__ B,
              const float* __restrict__ bias, float* __restrict__ C,
              int lda, long long bstrideA, int mpb)
{
    __shared__ float As[8][132];
    __shared__ float Bs[8][132];

    const int m0 = blockIdx.x * 128;
    const int n0 = blockIdx.y * 128;
    const int bidx = m0 / mpb;
    const int l0 = m0 % mpb;
    const float* Ab = A + (long long)bidx * bstrideA + l0;

    const int t  = threadIdx.x;
    const int tm = t >> 4;   // 0..15 (row group)
    const int tn = t & 15;   // 0..15 (col group)

    float acc[2][2][4][4];
#pragma unroll
    for (int i = 0; i < 2; ++i)
#pragma unroll
        for (int j = 0; j < 2; ++j)
#pragma unroll
            for (int ii = 0; ii < 4; ++ii)
#pragma unroll
                for (int jj = 0; jj < 4; ++jj) acc[i][j][ii][jj] = 0.f;

    // staging indices: one float4 per thread per matrix per K-tile
    const int skk = t >> 5;          // 0..7
    const int sm4 = (t & 31) * 4;    // 0..124

    for (int k0 = 0; k0 < D_MODEL; k0 += 8) {
        __syncthreads();
        {
            float4 av = *(const float4*)&Ab[(long long)(k0 + skk) * lda + sm4];
            float4 bv = *(const float4*)&B[(k0 + skk) * D_MODEL + n0 + sm4];
            *(float4*)&As[skk][sm4] = av;
            *(float4*)&Bs[skk][sm4] = bv;
        }
        __syncthreads();
#pragma unroll
        for (int kk = 0; kk < 8; ++kk) {
            float4 a0 = *(const float4*)&As[kk][tm * 4];
            float4 a1 = *(const float4*)&As[kk][tm * 4 + 64];
            float4 b0 = *(const float4*)&Bs[kk][tn * 4];
            float4 b1 = *(const float4*)&Bs[kk][tn * 4 + 64];
            float ar[2][4] = {{a0.x, a0.y, a0.z, a0.w}, {a1.x, a1.y, a1.z, a1.w}};
            float br[2][4] = {{b0.x, b0.y, b0.z, b0.w}, {b1.x, b1.y, b1.z, b1.w}};
#pragma unroll
            for (int i = 0; i < 2; ++i)
#pragma unroll
                for (int ii = 0; ii < 4; ++ii)
#pragma unroll
                    for (int j = 0; j < 2; ++j)
#pragma unroll
                        for (int jj = 0; jj < 4; ++jj)
                            acc[i][j][ii][jj] = fmaf(ar[i][ii], br[j][jj], acc[i][j][ii][jj]);
        }
    }

    if (!TOUT) {
#pragma unroll
        for (int i = 0; i < 2; ++i) {
#pragma unroll
            for (int ii = 0; ii < 4; ++ii) {
                int m = m0 + i * 64 + tm * 4 + ii;
#pragma unroll
                for (int j = 0; j < 2; ++j) {
                    int n = n0 + j * 64 + tn * 4;
                    float4 r;
                    r.x = acc[i][j][ii][0] + bias[n + 0];
                    r.y = acc[i][j][ii][1] + bias[n + 1];
                    r.z = acc[i][j][ii][2] + bias[n + 2];
                    r.w = acc[i][j][ii][3] + bias[n + 3];
                    *(float4*)&C[(long long)m * D_MODEL + n] = r;
                }
            }
        }
    } else {
#pragma unroll
        for (int i = 0; i < 2; ++i) {
#pragma unroll
            for (int ii = 0; ii < 4; ++ii) {
                int m = m0 + i * 64 + tm * 4 + ii;
                int bo = m / SEQ;
                int l  = m - bo * SEQ;
#pragma unroll
                for (int j = 0; j < 2; ++j) {
#pragma unroll
                    for (int jj = 0; jj < 4; ++jj) {
                        int n = n0 + j * 64 + tn * 4 + jj;
                        C[(long long)bo * D_MODEL * SEQ + (long long)n * SEQ + l] =
                            acc[i][j][ii][jj] + bias[n];
                    }
                }
            }
        }
    }
}

// ---------------------------------------------------------------------------
// Flash attention, fp32. 1 thread = 1 q row (q,O in regs), K/V tiles in LDS.
// Writes output TRANSPOSED: attnT[h*DK+d][b*SEQ+l]  (K-major for final GEMM).
// grid: (SEQ/256, NHEAD, BATCH), 256 threads.
// ---------------------------------------------------------------------------
#define KB 32

__global__ __launch_bounds__(256, 2)
void attn_fwd(const float* __restrict__ q, const float* __restrict__ k,
              const float* __restrict__ v, const int* __restrict__ mask,
              float* __restrict__ attnT)
{
    __shared__ float ks[KB][68];
    __shared__ float vs[KB][68];
    __shared__ float sbias[KB];

    const int t = threadIdx.x;
    const int h = blockIdx.y;
    const int b = blockIdx.z;
    const int l = blockIdx.x * 256 + t;

    // q row -> registers
    float qreg[64];
    const float* qp = q + ((long long)(b * SEQ + l) * D_MODEL + h * DK);
#pragma unroll
    for (int d4 = 0; d4 < 16; ++d4) {
        float4 f = *(const float4*)&qp[d4 * 4];
        qreg[d4 * 4 + 0] = f.x; qreg[d4 * 4 + 1] = f.y;
        qreg[d4 * 4 + 2] = f.z; qreg[d4 * 4 + 3] = f.w;
    }

    float o[64];
#pragma unroll
    for (int d = 0; d < 64; ++d) o[d] = 0.f;
    float mrun = NEG_INF;
    float lsum = 0.f;
    const float scale = 0.125f;  // 1/sqrt(64)

    for (int j0 = 0; j0 < SEQ; j0 += KB) {
        __syncthreads();
        // stage K/V tile: 2 float4 per thread per matrix
#pragma unroll
        for (int j = 0; j < 2; ++j) {
            int e  = t + j * 256;
            int r  = e >> 4;           // 0..31
            int d4 = (e & 15) * 4;     // 0..60
            long long src = (long long)(b * SEQ + j0 + r) * D_MODEL + h * DK + d4;
            *(float4*)&ks[r][d4] = *(const float4*)&k[src];
            *(float4*)&vs[r][d4] = *(const float4*)&v[src];
        }
        if (t < KB) sbias[t] = mask[b * SEQ + j0 + t] ? 0.f : NEG_INF;
        __syncthreads();

        float s[KB];
#pragma unroll
        for (int jj = 0; jj < KB; ++jj) {
            float dot = 0.f;
#pragma unroll
            for (int d4 = 0; d4 < 16; ++d4) {
                float4 k4 = *(const float4*)&ks[jj][d4 * 4];
                dot = fmaf(qreg[d4 * 4 + 0], k4.x, dot);
                dot = fmaf(qreg[d4 * 4 + 1], k4.y, dot);
                dot = fmaf(qreg[d4 * 4 + 2], k4.z, dot);
                dot = fmaf(qreg[d4 * 4 + 3], k4.w, dot);
            }
            s[jj] = fmaf(dot, scale, sbias[jj]);  // masked -> exactly -1e30 (absorbed)
        }

        float tmax = s[0];
#pragma unroll
        for (int jj = 1; jj < KB; ++jj) tmax = fmaxf(tmax, s[jj]);
        float mnew = fmaxf(mrun, tmax);
        float corr = __expf(mrun - mnew);

        float psum = 0.f;
#pragma unroll
        for (int jj = 0; jj < KB; ++jj) {
            s[jj] = __expf(s[jj] - mnew);
            psum += s[jj];
        }
        lsum = lsum * corr + psum;
#pragma unroll
        for (int d = 0; d < 64; ++d) o[d] *= corr;

#pragma unroll
        for (int jj = 0; jj < KB; ++jj) {
            float p = s[jj];
#pragma unroll
            for (int d4 = 0; d4 < 16; ++d4) {
                float4 v4 = *(const float4*)&vs[jj][d4 * 4];
                o[d4 * 4 + 0] = fmaf(p, v4.x, o[d4 * 4 + 0]);
                o[d4 * 4 + 1] = fmaf(p, v4.y, o[d4 * 4 + 1]);
                o[d4 * 4 + 2] = fmaf(p, v4.z, o[d4 * 4 + 2]);
                o[d4 * 4 + 3] = fmaf(p, v4.w, o[d4 * 4 + 3]);
            }
        }
        mrun = mnew;
    }

    float inv = 1.f / lsum;
#pragma unroll
    for (int d = 0; d < 64; ++d) {
        attnT[(long long)(h * DK + d) * (BATCH * SEQ) + b * SEQ + l] = o[d] * inv;
    }
}

// ---------------------------------------------------------------------------
extern "C" void kernel_launch(void* const* d_in, const int* in_sizes, int n_in,
                              void* d_out, int out_size, void* d_ws, size_t ws_size,
                              hipStream_t stream)
{
    const float* x    = (const float*)d_in[0];
    const int*   mask = (const int*)d_in[1];
    const float* Wq   = (const float*)d_in[2];
    const float* bq   = (const float*)d_in[3];
    const float* Wk   = (const float*)d_in[4];
    const float* bk   = (const float*)d_in[5];
    const float* Wv   = (const float*)d_in[6];
    const float* bv   = (const float*)d_in[7];
    const float* Wf   = (const float*)d_in[8];
    const float* bf   = (const float*)d_in[9];
    float* out = (float*)d_out;

    const long long MTOT = (long long)BATCH * SEQ;     // 8192
    float* q     = (float*)d_ws;
    float* kbuf  = q    + MTOT * D_MODEL;
    float* vbuf  = kbuf + MTOT * D_MODEL;
    float* attnT = vbuf + MTOT * D_MODEL;

    dim3 gGemm(BATCH * SEQ / 128, D_MODEL / 128);       // 64 x 8
    // projections: A = x (K-major), C row-major q/k/v [m][D_MODEL]
    gemm_atb<false><<<gGemm, 256, 0, stream>>>(x, Wq, bq, q,    SEQ, (long long)D_MODEL * SEQ, SEQ);
    gemm_atb<false><<<gGemm, 256, 0, stream>>>(x, Wk, bk, kbuf, SEQ, (long long)D_MODEL * SEQ, SEQ);
    gemm_atb<false><<<gGemm, 256, 0, stream>>>(x, Wv, bv, vbuf, SEQ, (long long)D_MODEL * SEQ, SEQ);

    dim3 gAttn(SEQ / 256, NHEAD, BATCH);                // 8 x 16 x 4
    attn_fwd<<<gAttn, 256, 0, stream>>>(q, kbuf, vbuf, mask, attnT);

    // final: A = attnT (K-major), write transposed into d_out
    gemm_atb<true><<<gGemm, 256, 0, stream>>>(attnT, Wf, bf, out, BATCH * SEQ, 0, BATCH * SEQ);
}

// Round 2
// 1011.194 us; speedup vs baseline: 2.0020x; 2.0020x over previous
//
#include <hip/hip_runtime.h>

#define D_MODEL 1024
#define NHEAD   16
#define DK      64
#define SEQ     2048
#define BATCH   4
#define NEG_INF (-1e30f)

typedef float f32x4 __attribute__((ext_vector_type(4)));
typedef short short8 __attribute__((ext_vector_type(8)));

__device__ __forceinline__ unsigned short f2bf_rne(float f) {
    unsigned u = __float_as_uint(f);
    u += 0x7fffu + ((u >> 16) & 1u);
    return (unsigned short)(u >> 16);
}
__device__ __forceinline__ uint2 pack4_trunc(float4 f) {
    uint2 r;
    r.x = (__float_as_uint(f.x) >> 16) | (__float_as_uint(f.y) & 0xffff0000u);
    r.y = (__float_as_uint(f.z) >> 16) | (__float_as_uint(f.w) & 0xffff0000u);
    return r;
}

// ---------------------------------------------------------------------------
// GEMM:  C[m][n] = sum_k A[k][m'] * B[k][n] + bias[n]   (unchanged fp32)
// ---------------------------------------------------------------------------
template<bool TOUT>
__global__ __launch_bounds__(256)
void gemm_atb(const float* __restrict__ A, const float* __restrict__ B,
              const float* __restrict__ bias, float* __restrict__ C,
              int lda, long long bstrideA, int mpb)
{
    __shared__ float As[8][132];
    __shared__ float Bs[8][132];

    const int m0 = blockIdx.x * 128;
    const int n0 = blockIdx.y * 128;
    const int bidx = m0 / mpb;
    const int l0 = m0 % mpb;
    const float* Ab = A + (long long)bidx * bstrideA + l0;

    const int t  = threadIdx.x;
    const int tm = t >> 4;
    const int tn = t & 15;

    float acc[2][2][4][4];
#pragma unroll
    for (int i = 0; i < 2; ++i)
#pragma unroll
        for (int j = 0; j < 2; ++j)
#pragma unroll
            for (int ii = 0; ii < 4; ++ii)
#pragma unroll
                for (int jj = 0; jj < 4; ++jj) acc[i][j][ii][jj] = 0.f;

    const int skk = t >> 5;
    const int sm4 = (t & 31) * 4;

    for (int k0 = 0; k0 < D_MODEL; k0 += 8) {
        __syncthreads();
        {
            float4 av = *(const float4*)&Ab[(long long)(k0 + skk) * lda + sm4];
            float4 bv = *(const float4*)&B[(k0 + skk) * D_MODEL + n0 + sm4];
            *(float4*)&As[skk][sm4] = av;
            *(float4*)&Bs[skk][sm4] = bv;
        }
        __syncthreads();
#pragma unroll
        for (int kk = 0; kk < 8; ++kk) {
            float4 a0 = *(const float4*)&As[kk][tm * 4];
            float4 a1 = *(const float4*)&As[kk][tm * 4 + 64];
            float4 b0 = *(const float4*)&Bs[kk][tn * 4];
            float4 b1 = *(const float4*)&Bs[kk][tn * 4 + 64];
            float ar[2][4] = {{a0.x, a0.y, a0.z, a0.w}, {a1.x, a1.y, a1.z, a1.w}};
            float br[2][4] = {{b0.x, b0.y, b0.z, b0.w}, {b1.x, b1.y, b1.z, b1.w}};
#pragma unroll
            for (int i = 0; i < 2; ++i)
#pragma unroll
                for (int ii = 0; ii < 4; ++ii)
#pragma unroll
                    for (int j = 0; j < 2; ++j)
#pragma unroll
                        for (int jj = 0; jj < 4; ++jj)
                            acc[i][j][ii][jj] = fmaf(ar[i][ii], br[j][jj], acc[i][j][ii][jj]);
        }
    }

    if (!TOUT) {
#pragma unroll
        for (int i = 0; i < 2; ++i) {
#pragma unroll
            for (int ii = 0; ii < 4; ++ii) {
                int m = m0 + i * 64 + tm * 4 + ii;
#pragma unroll
                for (int j = 0; j < 2; ++j) {
                    int n = n0 + j * 64 + tn * 4;
                    float4 r;
                    r.x = acc[i][j][ii][0] + bias[n + 0];
                    r.y = acc[i][j][ii][1] + bias[n + 1];
                    r.z = acc[i][j][ii][2] + bias[n + 2];
                    r.w = acc[i][j][ii][3] + bias[n + 3];
                    *(float4*)&C[(long long)m * D_MODEL + n] = r;
                }
            }
        }
    } else {
#pragma unroll
        for (int i = 0; i < 2; ++i) {
#pragma unroll
            for (int ii = 0; ii < 4; ++ii) {
                int m = m0 + i * 64 + tm * 4 + ii;
                int bo = m / SEQ;
                int l  = m - bo * SEQ;
#pragma unroll
                for (int j = 0; j < 2; ++j) {
#pragma unroll
                    for (int jj = 0; jj < 4; ++jj) {
                        int n = n0 + j * 64 + tn * 4 + jj;
                        C[(long long)bo * D_MODEL * SEQ + (long long)n * SEQ + l] =
                            acc[i][j][ii][jj] + bias[n];
                    }
                }
            }
        }
    }
}

// ---------------------------------------------------------------------------
// Flash attention with bf16 MFMA (16x16x32), fp32 softmax/accum.
// 4 waves/block; wave owns 32 q-rows (2 n-tiles); KV tile = 64 keys.
// Swapped QK^T: scoresT = mfma(A=K, B=Q) -> C[key][q].
// Output written transposed: attnT[h*DK+d][b*SEQ+l].
// grid: (SEQ/128, NHEAD, BATCH), 256 threads.
// ---------------------------------------------------------------------------
#define KB 64

__global__ __launch_bounds__(256, 2)
void attn_mfma(const float* __restrict__ q, const float* __restrict__ k,
               const float* __restrict__ v, const int* __restrict__ mask,
               float* __restrict__ attnT)
{
    __shared__ short ks[KB][72];     // K tile, [key][d], linear (reads 2-way)
    __shared__ short vsT[DK][72];    // V^T tile, [d][key], 16B-block XOR swizzled
    __shared__ short pT[4][16][72];  // per-wave P^T re-layout buffer [q][key]
    __shared__ float sbias[KB];

    const int t    = threadIdx.x;
    const int w    = t >> 6;
    const int lane = t & 63;
    const int lo16 = lane & 15;
    const int hi   = lane >> 4;

    const int h = blockIdx.y;
    const int b = blockIdx.z;
    const int q0 = blockIdx.x * 128 + w * 32;

    const float* kbase = k + ((long long)b * SEQ) * D_MODEL + h * DK;
    const float* vbase = v + ((long long)b * SEQ) * D_MODEL + h * DK;

    // ---- Q fragments (held in regs for whole kernel), RNE convert ----
    short8 qf[2][2];  // [nt][kstep]
#pragma unroll
    for (int nt = 0; nt < 2; ++nt) {
#pragma unroll
        for (int kk = 0; kk < 2; ++kk) {
            const float* qp = q + ((long long)(b * SEQ + q0 + nt * 16 + lo16)) * D_MODEL
                                + h * DK + kk * 32 + hi * 8;
            float4 f0 = *(const float4*)qp;
            float4 f1 = *(const float4*)(qp + 4);
            short8 s;
            s[0] = (short)f2bf_rne(f0.x); s[1] = (short)f2bf_rne(f0.y);
            s[2] = (short)f2bf_rne(f0.z); s[3] = (short)f2bf_rne(f0.w);
            s[4] = (short)f2bf_rne(f1.x); s[5] = (short)f2bf_rne(f1.y);
            s[6] = (short)f2bf_rne(f1.z); s[7] = (short)f2bf_rne(f1.w);
            qf[nt][kk] = s;
        }
    }

    f32x4 oacc[2][4];  // [nt][mt] : O^T[d=16mt+4hi+r][q=lo16]
#pragma unroll
    for (int nt = 0; nt < 2; ++nt)
#pragma unroll
        for (int mt = 0; mt < 4; ++mt) oacc[nt][mt] = (f32x4){0.f, 0.f, 0.f, 0.f};
    float mrun[2] = {NEG_INF, NEG_INF};
    float lsum[2] = {0.f, 0.f};

    // V^T swizzle params
    const int dstage  = t & 63;          // staging: this thread's d
    const int kgstage = t >> 6;          // staging: key group (16 keys)
    const int fsw_s   = (dstage & 7) ^ ((dstage >> 3) & 1);
    const int fsw_r   = (lo16 & 7) ^ ((lo16 >> 3) & 1);

    for (int kt = 0; kt < SEQ / KB; ++kt) {
        __syncthreads();
        // ---- stage K tile [key][d] (truncating bf16) ----
#pragma unroll
        for (int i = 0; i < 4; ++i) {
            int fi = t + i * 256;
            int row = fi >> 4, col4 = (fi & 15) * 4;
            float4 f = *(const float4*)&kbase[(long long)(kt * KB + row) * D_MODEL + col4];
            *(uint2*)&ks[row][col4] = pack4_trunc(f);
        }
        // ---- stage V^T tile [d][key], swizzled ----
        {
            float vr[16];
#pragma unroll
            for (int j = 0; j < 16; ++j)
                vr[j] = vbase[(long long)(kt * KB + kgstage * 16 + j) * D_MODEL + dstage];
#pragma unroll
            for (int jj = 0; jj < 4; ++jj) {
                uint2 w2;
                w2.x = (__float_as_uint(vr[jj * 4 + 0]) >> 16) | (__float_as_uint(vr[jj * 4 + 1]) & 0xffff0000u);
                w2.y = (__float_as_uint(vr[jj * 4 + 2]) >> 16) | (__float_as_uint(vr[jj * 4 + 3]) & 0xffff0000u);
                int bk = kgstage * 2 + (jj >> 1);
                int phys = ((bk ^ fsw_s) << 3) + ((jj & 1) << 2);
                *(uint2*)&vsT[dstage][phys] = w2;
            }
        }
        if (t < KB) sbias[t] = mask[b * SEQ + kt * KB + t] ? 0.f : NEG_INF;
        __syncthreads();

        // ---- load K / V^T fragments + score bias ----
        short8 kf[4][2], vf[4][2];
        f32x4 sb[4];
#pragma unroll
        for (int mt = 0; mt < 4; ++mt) {
#pragma unroll
            for (int kk = 0; kk < 2; ++kk) {
                kf[mt][kk] = *(const short8*)&ks[mt * 16 + lo16][kk * 32 + hi * 8];
                vf[mt][kk] = *(const short8*)&vsT[mt * 16 + lo16][((kk * 4 + hi) ^ fsw_r) << 3];
            }
            sb[mt] = *(const f32x4*)&sbias[mt * 16 + hi * 4];
        }

#pragma unroll
        for (int nt = 0; nt < 2; ++nt) {
            // QK^T (swapped): scoresT[key=16mt+4hi+r][q=lo16]
            f32x4 sc[4];
#pragma unroll
            for (int mt = 0; mt < 4; ++mt) {
                f32x4 a = (f32x4){0.f, 0.f, 0.f, 0.f};
                a = __builtin_amdgcn_mfma_f32_16x16x32_bf16(kf[mt][0], qf[nt][0], a, 0, 0, 0);
                a = __builtin_amdgcn_mfma_f32_16x16x32_bf16(kf[mt][1], qf[nt][1], a, 0, 0, 0);
                sc[mt] = a;
            }
            // online softmax (per lane: 16 keys of q=lo16; partners at xor 16,32)
            float p[4][4];
            float tmax = NEG_INF;
#pragma unroll
            for (int mt = 0; mt < 4; ++mt)
#pragma unroll
                for (int r = 0; r < 4; ++r) {
                    float s = fmaf(sc[mt][r], 0.125f, sb[mt][r]);
                    p[mt][r] = s;
                    tmax = fmaxf(tmax, s);
                }
            tmax = fmaxf(tmax, __shfl_xor(tmax, 16));
            tmax = fmaxf(tmax, __shfl_xor(tmax, 32));
            float mnew = fmaxf(mrun[nt], tmax);
            float corr = __expf(mrun[nt] - mnew);
            mrun[nt] = mnew;
            float psum = 0.f;
#pragma unroll
            for (int mt = 0; mt < 4; ++mt)
#pragma unroll
                for (int r = 0; r < 4; ++r) {
                    float e = __expf(p[mt][r] - mnew);
                    p[mt][r] = e;
                    psum += e;
                }
            psum += __shfl_xor(psum, 16);
            psum += __shfl_xor(psum, 32);
            lsum[nt] = lsum[nt] * corr + psum;
#pragma unroll
            for (int mt = 0; mt < 4; ++mt) oacc[nt][mt] *= corr;

            // P^T -> LDS re-layout (C-layout write, B-frag read)
#pragma unroll
            for (int mt = 0; mt < 4; ++mt) {
                uint2 w2;
                w2.x = (unsigned)f2bf_rne(p[mt][0]) | ((unsigned)f2bf_rne(p[mt][1]) << 16);
                w2.y = (unsigned)f2bf_rne(p[mt][2]) | ((unsigned)f2bf_rne(p[mt][3]) << 16);
                *(uint2*)&pT[w][lo16][mt * 16 + hi * 4] = w2;
            }
            asm volatile("s_waitcnt lgkmcnt(0)" ::: "memory");
            __builtin_amdgcn_sched_barrier(0);
            short8 pf0 = *(const short8*)&pT[w][lo16][hi * 8];
            short8 pf1 = *(const short8*)&pT[w][lo16][32 + hi * 8];

            // PV: O^T[d][q] += V^T · P^T
#pragma unroll
            for (int mt = 0; mt < 4; ++mt) {
                oacc[nt][mt] = __builtin_amdgcn_mfma_f32_16x16x32_bf16(vf[mt][0], pf0, oacc[nt][mt], 0, 0, 0);
                oacc[nt][mt] = __builtin_amdgcn_mfma_f32_16x16x32_bf16(vf[mt][1], pf1, oacc[nt][mt], 0, 0, 0);
            }
        }
    }

    // ---- epilogue: normalize + write transposed ----
    float* obase = attnT + (long long)(h * DK) * (BATCH * SEQ) + b * SEQ;
#pragma unroll
    for (int nt = 0; nt < 2; ++nt) {
        float inv = 1.f / lsum[nt];
        int col = q0 + nt * 16 + lo16;
#pragma unroll
        for (int mt = 0; mt < 4; ++mt)
#pragma unroll
            for (int r = 0; r < 4; ++r) {
                int d = mt * 16 + hi * 4 + r;
                obase[(long long)d * (BATCH * SEQ) + col] = oacc[nt][mt][r] * inv;
            }
    }
}

// ---------------------------------------------------------------------------
extern "C" void kernel_launch(void* const* d_in, const int* in_sizes, int n_in,
                              void* d_out, int out_size, void* d_ws, size_t ws_size,
                              hipStream_t stream)
{
    const float* x    = (const float*)d_in[0];
    const int*   mask = (const int*)d_in[1];
    const float* Wq   = (const float*)d_in[2];
    const float* bq   = (const float*)d_in[3];
    const float* Wk   = (const float*)d_in[4];
    const float* bk   = (const float*)d_in[5];
    const float* Wv   = (const float*)d_in[6];
    const float* bv   = (const float*)d_in[7];
    const float* Wf   = (const float*)d_in[8];
    const float* bf   = (const float*)d_in[9];
    float* out = (float*)d_out;

    const long long MTOT = (long long)BATCH * SEQ;
    float* qb    = (float*)d_ws;
    float* kbuf  = qb   + MTOT * D_MODEL;
    float* vbuf  = kbuf + MTOT * D_MODEL;
    float* attnT = vbuf + MTOT * D_MODEL;

    dim3 gGemm(BATCH * SEQ / 128, D_MODEL / 128);
    gemm_atb<false><<<gGemm, 256, 0, stream>>>(x, Wq, bq, qb,   SEQ, (long long)D_MODEL * SEQ, SEQ);
    gemm_atb<false><<<gGemm, 256, 0, stream>>>(x, Wk, bk, kbuf, SEQ, (long long)D_MODEL * SEQ, SEQ);
    gemm_atb<false><<<gGemm, 256, 0, stream>>>(x, Wv, bv, vbuf, SEQ, (long long)D_MODEL * SEQ, SEQ);

    dim3 gAttn(SEQ / 128, NHEAD, BATCH);
    attn_mfma<<<gAttn, 256, 0, stream>>>(qb, kbuf, vbuf, mask, attnT);

    gemm_atb<true><<<gGemm, 256, 0, stream>>>(attnT, Wf, bf, out, BATCH * SEQ, 0, BATCH * SEQ);
}

// Round 3
// 309.098 us; speedup vs baseline: 6.5495x; 3.2714x over previous
//
#include <hip/hip_runtime.h>

#define D_MODEL 1024
#define NHEAD   16
#define DK      64
#define SEQ     2048
#define BATCH   4
#define MTOT    (BATCH * SEQ)   // 8192
#define NEG_INF (-1e30f)

typedef float    f32x4 __attribute__((ext_vector_type(4)));
typedef _Float16 half8 __attribute__((ext_vector_type(8)));

__device__ __forceinline__ unsigned hb(float f) {
    _Float16 h = (_Float16)f;                       // v_cvt_f16_f32 (RNE)
    return (unsigned)__builtin_bit_cast(unsigned short, h);
}
__device__ __forceinline__ uint2 pack4h(float a, float b, float c, float d) {
    uint2 r; r.x = hb(a) | (hb(b) << 16); r.y = hb(c) | (hb(d) << 16); return r;
}

// ---------------------------------------------------------------------------
// Transpose + fp32->f16 convert:  src fp32 [R][C] -> dst f16 [C][R]
// grid (C/32, R/32, nbatch), 256 threads.
// ---------------------------------------------------------------------------
__global__ __launch_bounds__(256)
void transpose_cvt(const float* __restrict__ src, _Float16* __restrict__ dst,
                   int R, int C, long long sB, long long dB)
{
    __shared__ float tile[32][33];
    const int t = threadIdx.x;
    src += (long long)blockIdx.z * sB;
    dst += (long long)blockIdx.z * dB;
    const int r0 = blockIdx.y * 32, c0 = blockIdx.x * 32;
    const int lr = t >> 3, lc = (t & 7) * 4;

    float4 f = *(const float4*)&src[(long long)(r0 + lr) * C + c0 + lc];
    tile[lr][lc + 0] = f.x; tile[lr][lc + 1] = f.y;
    tile[lr][lc + 2] = f.z; tile[lr][lc + 3] = f.w;
    __syncthreads();
    uint2 o = pack4h(tile[lc + 0][lr], tile[lc + 1][lr],
                     tile[lc + 2][lr], tile[lc + 3][lr]);
    *(uint2*)&dst[(long long)(c0 + lr) * R + r0 + lc] = o;
}

// ---------------------------------------------------------------------------
// f16 MFMA GEMM:  C[m][n] = sum_k A[m][k] * B^T[n][k] + bias[n]
// M=8192, N=1024, K=1024 fixed. Tile 128x128, BK=32, 4 waves (2x2), each wave
// 4x4 frags of 16x16x32. global_load_lds staging with chunk-XOR swizzle:
// phys 16B-chunk = logical ^ ((row>>1)&3)  (2-way max on b128 frag reads).
// TOUT=false: C fp32 [m][1024].  TOUT=true: C = d_out [BATCH][N][SEQ].
// grid: 512 blocks x 256 threads.
// ---------------------------------------------------------------------------
template<bool TOUT>
__global__ __launch_bounds__(256)
void gemm_f16(const _Float16* __restrict__ A, const _Float16* __restrict__ B,
              const float* __restrict__ bias, float* __restrict__ C)
{
    __shared__ __align__(16) _Float16 As[128 * 32];
    __shared__ __align__(16) _Float16 Bs[128 * 32];

    const int t = threadIdx.x, w = t >> 6, l = t & 63;
    const int lo16 = l & 15, hi = l >> 4;
    const int bid = blockIdx.x;
    const int swz = (bid & 7) * 64 + (bid >> 3);    // 512 % 8 == 0: bijective
    const int bm = swz & 63, bn = swz >> 6;
    const int wr = w >> 1, wc = w & 1;

    f32x4 acc[4][4];
#pragma unroll
    for (int mi = 0; mi < 4; ++mi)
#pragma unroll
        for (int ni = 0; ni < 4; ++ni) acc[mi][ni] = (f32x4){0.f, 0.f, 0.f, 0.f};

    // staging: per wave 2 instrs/matrix; instr j covers rows w*32+j*16+(l>>2),
    // lane's 16B = 8 halfs at source k-chunk (l&3)^((l>>3)&3)  (pre-swizzle)
    const int srow   = l >> 2;
    const int schunk = (l & 3) ^ ((l >> 3) & 3);
    const _Float16* Ag = A + (long long)(bm * 128 + w * 32 + srow) * 1024 + schunk * 8;
    const _Float16* Bg = B + (long long)(bn * 128 + w * 32 + srow) * 1024 + schunk * 8;
    const int ldsOff = (w * 32) * 32;               // halfs

    const int xr = (lo16 >> 1) & 3;                 // read-side XOR

    for (int k0 = 0; k0 < 1024; k0 += 32) {
        __syncthreads();
        __builtin_amdgcn_global_load_lds(reinterpret_cast<const unsigned int*>(Ag + k0),
                                         reinterpret_cast<unsigned int*>(&As[ldsOff]), 16, 0, 0);
        __builtin_amdgcn_global_load_lds(reinterpret_cast<const unsigned int*>(Ag + k0 + 16 * 1024),
                                         reinterpret_cast<unsigned int*>(&As[ldsOff + 16 * 32]), 16, 0, 0);
        __builtin_amdgcn_global_load_lds(reinterpret_cast<const unsigned int*>(Bg + k0),
                                         reinterpret_cast<unsigned int*>(&Bs[ldsOff]), 16, 0, 0);
        __builtin_amdgcn_global_load_lds(reinterpret_cast<const unsigned int*>(Bg + k0 + 16 * 1024),
                                         reinterpret_cast<unsigned int*>(&Bs[ldsOff + 16 * 32]), 16, 0, 0);
        __syncthreads();

        half8 af[4], bf[4];
#pragma unroll
        for (int mi = 0; mi < 4; ++mi)
            af[mi] = *(const half8*)&As[(wr * 64 + mi * 16 + lo16) * 32 + ((hi ^ xr) << 3)];
#pragma unroll
        for (int ni = 0; ni < 4; ++ni)
            bf[ni] = *(const half8*)&Bs[(wc * 64 + ni * 16 + lo16) * 32 + ((hi ^ xr) << 3)];
#pragma unroll
        for (int mi = 0; mi < 4; ++mi)
#pragma unroll
            for (int ni = 0; ni < 4; ++ni)
                acc[mi][ni] = __builtin_amdgcn_mfma_f32_16x16x32_f16(af[mi], bf[ni], acc[mi][ni], 0, 0, 0);
    }

    if (!TOUT) {
#pragma unroll
        for (int mi = 0; mi < 4; ++mi) {
            const int m = bm * 128 + wr * 64 + mi * 16 + hi * 4;
#pragma unroll
            for (int ni = 0; ni < 4; ++ni) {
                const int n = bn * 128 + wc * 64 + ni * 16 + lo16;
                const float bv = bias[n];
#pragma unroll
                for (int r = 0; r < 4; ++r)
                    C[(long long)(m + r) * D_MODEL + n] = acc[mi][ni][r] + bv;
            }
        }
    } else {
#pragma unroll
        for (int mi = 0; mi < 4; ++mi) {
            const int m  = bm * 128 + wr * 64 + mi * 16 + hi * 4;
            const int bo = m >> 11;               // / SEQ
            const int ll = m & (SEQ - 1);
#pragma unroll
            for (int ni = 0; ni < 4; ++ni) {
                const int n = bn * 128 + wc * 64 + ni * 16 + lo16;
                const float bv = bias[n];
                float4 o;
                o.x = acc[mi][ni][0] + bv; o.y = acc[mi][ni][1] + bv;
                o.z = acc[mi][ni][2] + bv; o.w = acc[mi][ni][3] + bv;
                *(float4*)&C[(long long)bo * D_MODEL * SEQ + (long long)n * SEQ + ll] = o;
            }
        }
    }
}

// ---------------------------------------------------------------------------
// Flash attention, f16 MFMA (16x16x32), fp32 softmax/accum.
// Round-2 structure; epilogue LDS-bounces O to f16 [m][d] (attnO).
// grid: (SEQ/128, NHEAD, BATCH), 256 threads.
// ---------------------------------------------------------------------------
#define KB 64

__global__ __launch_bounds__(256, 2)
void attn_mfma(const float* __restrict__ q, const float* __restrict__ k,
               const float* __restrict__ v, const int* __restrict__ mask,
               _Float16* __restrict__ attnO)
{
    __shared__ __align__(16) _Float16 ks[KB][72];
    __shared__ __align__(16) _Float16 vsT[DK][72];
    __shared__ __align__(16) _Float16 pT[4][16][72];
    __shared__ float sbias[KB];

    const int t    = threadIdx.x;
    const int w    = t >> 6;
    const int lane = t & 63;
    const int lo16 = lane & 15;
    const int hi   = lane >> 4;

    const int h = blockIdx.y;
    const int b = blockIdx.z;
    const int q0 = blockIdx.x * 128 + w * 32;

    const float* kbase = k + ((long long)b * SEQ) * D_MODEL + h * DK;
    const float* vbase = v + ((long long)b * SEQ) * D_MODEL + h * DK;

    // Q fragments in regs
    half8 qf[2][2];
#pragma unroll
    for (int nt = 0; nt < 2; ++nt) {
#pragma unroll
        for (int kk = 0; kk < 2; ++kk) {
            const float* qp = q + ((long long)(b * SEQ + q0 + nt * 16 + lo16)) * D_MODEL
                                + h * DK + kk * 32 + hi * 8;
            float4 f0 = *(const float4*)qp;
            float4 f1 = *(const float4*)(qp + 4);
            half8 s;
            s[0] = (_Float16)f0.x; s[1] = (_Float16)f0.y;
            s[2] = (_Float16)f0.z; s[3] = (_Float16)f0.w;
            s[4] = (_Float16)f1.x; s[5] = (_Float16)f1.y;
            s[6] = (_Float16)f1.z; s[7] = (_Float16)f1.w;
            qf[nt][kk] = s;
        }
    }

    f32x4 oacc[2][4];
#pragma unroll
    for (int nt = 0; nt < 2; ++nt)
#pragma unroll
        for (int mt = 0; mt < 4; ++mt) oacc[nt][mt] = (f32x4){0.f, 0.f, 0.f, 0.f};
    float mrun[2] = {NEG_INF, NEG_INF};
    float lsum[2] = {0.f, 0.f};

    const int dstage  = t & 63;
    const int kgstage = t >> 6;
    const int fsw_s   = (dstage & 7) ^ ((dstage >> 3) & 1);
    const int fsw_r   = (lo16 & 7) ^ ((lo16 >> 3) & 1);

    for (int kt = 0; kt < SEQ / KB; ++kt) {
        __syncthreads();
        // stage K tile [key][d]
#pragma unroll
        for (int i = 0; i < 4; ++i) {
            int fi = t + i * 256;
            int row = fi >> 4, col4 = (fi & 15) * 4;
            float4 f = *(const float4*)&kbase[(long long)(kt * KB + row) * D_MODEL + col4];
            *(uint2*)&ks[row][col4] = pack4h(f.x, f.y, f.z, f.w);
        }
        // stage V^T tile [d][key], 16B-block XOR swizzled
        {
            float vr[16];
#pragma unroll
            for (int j = 0; j < 16; ++j)
                vr[j] = vbase[(long long)(kt * KB + kgstage * 16 + j) * D_MODEL + dstage];
#pragma unroll
            for (int jj = 0; jj < 4; ++jj) {
                uint2 w2 = pack4h(vr[jj * 4 + 0], vr[jj * 4 + 1], vr[jj * 4 + 2], vr[jj * 4 + 3]);
                int bk = kgstage * 2 + (jj >> 1);
                int phys = ((bk ^ fsw_s) << 3) + ((jj & 1) << 2);
                *(uint2*)&vsT[dstage][phys] = w2;
            }
        }
        if (t < KB) sbias[t] = mask[b * SEQ + kt * KB + t] ? 0.f : NEG_INF;
        __syncthreads();

        half8 kf[4][2], vf[4][2];
        f32x4 sb[4];
#pragma unroll
        for (int mt = 0; mt < 4; ++mt) {
#pragma unroll
            for (int kk = 0; kk < 2; ++kk) {
                kf[mt][kk] = *(const half8*)&ks[mt * 16 + lo16][kk * 32 + hi * 8];
                vf[mt][kk] = *(const half8*)&vsT[mt * 16 + lo16][((kk * 4 + hi) ^ fsw_r) << 3];
            }
            sb[mt] = *(const f32x4*)&sbias[mt * 16 + hi * 4];
        }

#pragma unroll
        for (int nt = 0; nt < 2; ++nt) {
            f32x4 sc[4];
#pragma unroll
            for (int mt = 0; mt < 4; ++mt) {
                f32x4 a = (f32x4){0.f, 0.f, 0.f, 0.f};
                a = __builtin_amdgcn_mfma_f32_16x16x32_f16(kf[mt][0], qf[nt][0], a, 0, 0, 0);
                a = __builtin_amdgcn_mfma_f32_16x16x32_f16(kf[mt][1], qf[nt][1], a, 0, 0, 0);
                sc[mt] = a;
            }
            float p[4][4];
            float tmax = NEG_INF;
#pragma unroll
            for (int mt = 0; mt < 4; ++mt)
#pragma unroll
                for (int r = 0; r < 4; ++r) {
                    float s = fmaf(sc[mt][r], 0.125f, sb[mt][r]);
                    p[mt][r] = s;
                    tmax = fmaxf(tmax, s);
                }
            tmax = fmaxf(tmax, __shfl_xor(tmax, 16));
            tmax = fmaxf(tmax, __shfl_xor(tmax, 32));
            float mnew = fmaxf(mrun[nt], tmax);
            float corr = __expf(mrun[nt] - mnew);
            mrun[nt] = mnew;
            float psum = 0.f;
#pragma unroll
            for (int mt = 0; mt < 4; ++mt)
#pragma unroll
                for (int r = 0; r < 4; ++r) {
                    float e = __expf(p[mt][r] - mnew);
                    p[mt][r] = e;
                    psum += e;
                }
            psum += __shfl_xor(psum, 16);
            psum += __shfl_xor(psum, 32);
            lsum[nt] = lsum[nt] * corr + psum;
#pragma unroll
            for (int mt = 0; mt < 4; ++mt) oacc[nt][mt] *= corr;

#pragma unroll
            for (int mt = 0; mt < 4; ++mt)
                *(uint2*)&pT[w][lo16][mt * 16 + hi * 4] =
                    pack4h(p[mt][0], p[mt][1], p[mt][2], p[mt][3]);
            asm volatile("s_waitcnt lgkmcnt(0)" ::: "memory");
            __builtin_amdgcn_sched_barrier(0);
            half8 pf0 = *(const half8*)&pT[w][lo16][hi * 8];
            half8 pf1 = *(const half8*)&pT[w][lo16][32 + hi * 8];

#pragma unroll
            for (int mt = 0; mt < 4; ++mt) {
                oacc[nt][mt] = __builtin_amdgcn_mfma_f32_16x16x32_f16(vf[mt][0], pf0, oacc[nt][mt], 0, 0, 0);
                oacc[nt][mt] = __builtin_amdgcn_mfma_f32_16x16x32_f16(vf[mt][1], pf1, oacc[nt][mt], 0, 0, 0);
            }
        }
    }

    // epilogue: normalize, LDS-bounce transpose, write f16 [m][d]
#pragma unroll
    for (int nt = 0; nt < 2; ++nt) {
        float inv = 1.f / lsum[nt];
#pragma unroll
        for (int mt = 0; mt < 4; ++mt)
            *(uint2*)&pT[w][lo16][mt * 16 + hi * 4] =
                pack4h(oacc[nt][mt][0] * inv, oacc[nt][mt][1] * inv,
                       oacc[nt][mt][2] * inv, oacc[nt][mt][3] * inv);
        asm volatile("s_waitcnt lgkmcnt(0)" ::: "memory");
        __builtin_amdgcn_sched_barrier(0);
#pragma unroll
        for (int j = 0; j < 2; ++j) {
            int idx = lane + j * 64;
            int qr = idx >> 3, c8 = idx & 7;
            half8 row = *(const half8*)&pT[w][qr][c8 * 8];
            *(half8*)&attnO[(long long)(b * SEQ + q0 + nt * 16 + qr) * D_MODEL + h * DK + c8 * 8] = row;
        }
    }
}

// ---------------------------------------------------------------------------
extern "C" void kernel_launch(void* const* d_in, const int* in_sizes, int n_in,
                              void* d_out, int out_size, void* d_ws, size_t ws_size,
                              hipStream_t stream)
{
    const float* x    = (const float*)d_in[0];
    const int*   mask = (const int*)d_in[1];
    const float* Wq   = (const float*)d_in[2];
    const float* bq   = (const float*)d_in[3];
    const float* Wk   = (const float*)d_in[4];
    const float* bk   = (const float*)d_in[5];
    const float* Wv   = (const float*)d_in[6];
    const float* bv   = (const float*)d_in[7];
    const float* Wf   = (const float*)d_in[8];
    const float* bf   = (const float*)d_in[9];
    float* out = (float*)d_out;

    // workspace layout (125.8 MB): xt (reused as attnO) | 4x WT | q | k | v
    _Float16* xt  = (_Float16*)d_ws;                       // [8192][1024]
    _Float16* WTq = xt  + (size_t)MTOT * D_MODEL;          // [1024][1024] each
    _Float16* WTk = WTq + (size_t)D_MODEL * D_MODEL;
    _Float16* WTv = WTk + (size_t)D_MODEL * D_MODEL;
    _Float16* WTf = WTv + (size_t)D_MODEL * D_MODEL;
    float* qb = (float*)(WTf + (size_t)D_MODEL * D_MODEL); // fp32 [8192][1024] each
    float* kb = qb + (size_t)MTOT * D_MODEL;
    float* vb = kb + (size_t)MTOT * D_MODEL;

    // pre-passes: transpose+convert
    dim3 gTx(SEQ / 32, D_MODEL / 32, BATCH);
    transpose_cvt<<<gTx, 256, 0, stream>>>(x, xt, D_MODEL, SEQ,
                                           (long long)D_MODEL * SEQ, (long long)SEQ * D_MODEL);
    dim3 gTw(D_MODEL / 32, D_MODEL / 32, 1);
    transpose_cvt<<<gTw, 256, 0, stream>>>(Wq, WTq, D_MODEL, D_MODEL, 0, 0);
    transpose_cvt<<<gTw, 256, 0, stream>>>(Wk, WTk, D_MODEL, D_MODEL, 0, 0);
    transpose_cvt<<<gTw, 256, 0, stream>>>(Wv, WTv, D_MODEL, D_MODEL, 0, 0);
    transpose_cvt<<<gTw, 256, 0, stream>>>(Wf, WTf, D_MODEL, D_MODEL, 0, 0);

    // projections
    gemm_f16<false><<<512, 256, 0, stream>>>(xt, WTq, bq, qb);
    gemm_f16<false><<<512, 256, 0, stream>>>(xt, WTk, bk, kb);
    gemm_f16<false><<<512, 256, 0, stream>>>(xt, WTv, bv, vb);

    // attention (writes f16 attn output into xt slot — xt is dead now)
    dim3 gAttn(SEQ / 128, NHEAD, BATCH);
    attn_mfma<<<gAttn, 256, 0, stream>>>(qb, kb, vb, mask, xt);

    // final projection, transposed store into d_out
    gemm_f16<true><<<512, 256, 0, stream>>>(xt, WTf, bf, out);
}